// Round 3
// baseline (615.973 us; speedup 1.0000x reference)
//
#include <hip/hip_runtime.h>

// QINCoStep — bs=2048, d=128, K=256, h=256, fp32 in/out.
// Round 3:
//  - blk0 GEMM1 eliminated algebraically: h_pre0 = H1pre[k] + U1[b] (precomputed f32)
//  - blk0 GEMM2 barrier-free (B-frags from global adds+relu, no LDS)
//  - split accumulator chains zs (hi*hi) / zb (cross terms) for MFMA ILP
//  - 2 m-tiles per wave (halves LDS B-read traffic per MFMA)
//  - truncation splits packed with v_perm_b32
//
// ws layout (floats):
//   0       WzT   16384      16384  WxT   16384
//   32768   W1T0  32768      65536  W2T0  32768
//   98304   W1T1  32768      131072 W2T1  32768
//   163840  z0    32768      196608 u     262144
//   458752  H1pre 65536      524288 U1    524288
//   1048576 wsmin 16384 (2048*4 float2)
//   1064960 codes 2048 (int)
//   1067008 frag region F: 32768 uint4 (512 KB)

typedef short bf8_t __attribute__((ext_vector_type(8)));
typedef float f32x16 __attribute__((ext_vector_type(16)));

__device__ inline unsigned short f2bh(float x) {
    unsigned u = __float_as_uint(x);
    u += 0x7fffu + ((u >> 16) & 1u);
    return (unsigned short)(u >> 16);
}
__device__ inline float bh2f(unsigned short h) {
    return __uint_as_float(((unsigned)h) << 16);
}
__device__ inline f32x16 mfma_bf(uint4 a, uint4 b, f32x16 c) {
    bf8_t av = __builtin_bit_cast(bf8_t, a);
    bf8_t bv = __builtin_bit_cast(bf8_t, b);
    return __builtin_amdgcn_mfma_f32_32x32x16_bf16(av, bv, c, 0, 0, 0);
}
// pack hi16(x) into low half, hi16(y) into high half (1 v_perm_b32)
__device__ inline unsigned packhi(float x, float y) {
    return __builtin_amdgcn_perm(__float_as_uint(y), __float_as_uint(x), 0x07060302u);
}
__device__ inline float tres(float v) {   // exact residual of bf16-truncation
    return v - __uint_as_float(__float_as_uint(v) & 0xFFFF0000u);
}

// ---------------- prep kernels ----------------

__global__ __launch_bounds__(256) void k_transpose(
    const float* __restrict__ Wc,
    const float* __restrict__ W1a, const float* __restrict__ W2a,
    const float* __restrict__ W1b, const float* __restrict__ W2b,
    float* __restrict__ WzT, float* __restrict__ WxT,
    float* __restrict__ W1Ta, float* __restrict__ W2Ta,
    float* __restrict__ W1Tb, float* __restrict__ W2Tb)
{
    int g = blockIdx.x * 256 + threadIdx.x;   // 0 .. 163839
    if (g < 16384) {
        int j = g >> 7, d = g & 127;
        WzT[g] = Wc[d * 256 + j];
    } else if (g < 32768) {
        int e = g - 16384; int j = e >> 7, d = e & 127;
        WxT[e] = Wc[d * 256 + 128 + j];
    } else if (g < 65536) {
        int e = g - 32768; int d = e >> 8, h = e & 255;
        W1Ta[e] = W1a[h * 128 + d];
    } else if (g < 98304) {
        int e = g - 65536; int h = e >> 7, i = e & 127;
        W2Ta[e] = W2a[i * 256 + h];
    } else if (g < 131072) {
        int e = g - 98304; int d = e >> 8, h = e & 255;
        W1Tb[e] = W1b[h * 128 + d];
    } else if (g < 163840) {
        int e = g - 131072; int h = e >> 7, i = e & 127;
        W2Tb[e] = W2b[i * 256 + h];
    }
}

// Pack weights into A-fragments (hi/lo bf16, RNE) for mfma 32x32x16.
// lane -> row m = 32*mt + (lane&31), cols 16*kt + 8*(lane>>5) + j.
__global__ __launch_bounds__(256) void k_pack(
    const float* __restrict__ W1a, const float* __restrict__ W2a,
    const float* __restrict__ W1b, const float* __restrict__ W2b,
    uint4* __restrict__ F)
{
    int idx = blockIdx.x * 256 + threadIdx.x;   // 0..16383
    int mat = idx >> 12, fp = idx & 4095;
    int tile = fp >> 6, lane = fp & 63;
    const float* src;
    if (mat == 0 || mat == 2) {                 // W1-type: [256][128], 8 mt x 8 kt
        const float* W = (mat == 0) ? W1a : W1b;
        int mt = tile >> 3, kt = tile & 7;
        int m = 32 * mt + (lane & 31);
        int c0 = 16 * kt + 8 * ((lane >> 5) & 1);
        src = W + m * 128 + c0;
    } else {                                    // W2-type: [128][256], 4 mt x 16 kt
        const float* W = (mat == 1) ? W2a : W2b;
        int mt = tile >> 4, kt = tile & 15;
        int m = 32 * mt + (lane & 31);
        int c0 = 16 * kt + 8 * ((lane >> 5) & 1);
        src = W + m * 256 + c0;
    }
    unsigned short hs[8], ls[8];
#pragma unroll
    for (int j = 0; j < 8; ++j) {
        float v = src[j];
        unsigned short h = f2bh(v);
        hs[j] = h;
        ls[j] = f2bh(v - bh2f(h));
    }
    uint4 hv, lv;
    hv.x = (unsigned)hs[0] | ((unsigned)hs[1] << 16);
    hv.y = (unsigned)hs[2] | ((unsigned)hs[3] << 16);
    hv.z = (unsigned)hs[4] | ((unsigned)hs[5] << 16);
    hv.w = (unsigned)hs[6] | ((unsigned)hs[7] << 16);
    lv.x = (unsigned)ls[0] | ((unsigned)ls[1] << 16);
    lv.y = (unsigned)ls[2] | ((unsigned)ls[3] << 16);
    lv.z = (unsigned)ls[4] | ((unsigned)ls[5] << 16);
    lv.w = (unsigned)ls[6] | ((unsigned)ls[7] << 16);
    uint4* dst = F + mat * 8192 + tile * 128;
    dst[lane] = hv;
    dst[64 + lane] = lv;
}

__global__ __launch_bounds__(256) void k_z0(
    const float* __restrict__ cb, const float* __restrict__ bc,
    const float* __restrict__ WzT, float* __restrict__ z0)
{
    int g = blockIdx.x * 256 + threadIdx.x;   // 0..32767
    int k = g >> 7, d = g & 127;
    float acc = bc[d] + cb[k * 128 + d];
    for (int j = 0; j < 128; ++j)
        acc = fmaf(cb[k * 128 + j], WzT[j * 128 + d], acc);
    z0[g] = acc;
}

__global__ __launch_bounds__(256) void k_u(
    const float* __restrict__ xhat, const float* __restrict__ WxT,
    float* __restrict__ u)
{
    int g = blockIdx.x * 256 + threadIdx.x;   // 0..262143
    int bl = g >> 7, d = g & 127;
    const float* xr = xhat + bl * 128;
    float acc = 0.f;
    for (int j = 0; j < 128; ++j)
        acc = fmaf(xr[j], WxT[j * 128 + d], acc);
    u[g] = acc;
}

// dst[r][h] = sum_i src[r][i] * W1[h][i]; 4 rows per workgroup, thread = h.
__global__ __launch_bounds__(256) void k_preh(
    const float* __restrict__ src, const float* __restrict__ W1,
    float* __restrict__ dst)
{
    __shared__ float s[4][128];
    const int t = threadIdx.x;
    const int r0 = blockIdx.x * 4;
#pragma unroll
    for (int e = t; e < 512; e += 256)
        s[e >> 7][e & 127] = src[(r0 + (e >> 7)) * 128 + (e & 127)];
    __syncthreads();
    float a0 = 0.f, a1 = 0.f, a2 = 0.f, a3 = 0.f;
    const float* wr = W1 + t * 128;
    for (int i = 0; i < 128; i += 4) {
        float4 w = *(const float4*)(wr + i);
        a0 = fmaf(s[0][i], w.x, fmaf(s[0][i+1], w.y, fmaf(s[0][i+2], w.z, fmaf(s[0][i+3], w.w, a0))));
        a1 = fmaf(s[1][i], w.x, fmaf(s[1][i+1], w.y, fmaf(s[1][i+2], w.z, fmaf(s[1][i+3], w.w, a1))));
        a2 = fmaf(s[2][i], w.x, fmaf(s[2][i+1], w.y, fmaf(s[2][i+2], w.z, fmaf(s[2][i+3], w.w, a2))));
        a3 = fmaf(s[3][i], w.x, fmaf(s[3][i+1], w.y, fmaf(s[3][i+2], w.z, fmaf(s[3][i+3], w.w, a3))));
    }
    dst[(r0 + 0) * 256 + t] = a0;
    dst[(r0 + 1) * 256 + t] = a1;
    dst[(r0 + 2) * 256 + t] = a2;
    dst[(r0 + 3) * 256 + t] = a3;
}

// ---------------- main MFMA dist kernel ----------------
// wg: 4 waves, one b, 64 codes. wave = (wq = wave>>1, wn = wave&1).
// G2 (both blocks): wave accumulates mi in {2wq, 2wq+1} for its wn-half.
// blk1 G1: 4 chunks of 64 h; wave does mtile 2c+wq.
__global__ __launch_bounds__(256, 3) void k_dist_mfma(
    const float* __restrict__ z0, const float* __restrict__ u,
    const float* __restrict__ xhat, const float* __restrict__ x,
    const float* __restrict__ H1pre, const float* __restrict__ U1,
    const uint4* __restrict__ W2f0, const uint4* __restrict__ W1f1,
    const uint4* __restrict__ W2f1, float2* __restrict__ wsmin)
{
    __shared__ unsigned short Zh[64][136], Zl[64][136];   // 34.8 KB (272B rows, 16B-aligned)
    __shared__ unsigned short Hh[64][72],  Hl[64][72];    // 18.4 KB (144B rows, 16B-aligned)
    __shared__ float diffv[128];
    __shared__ float red[2][64];

    const int t = threadIdx.x;
    const int b  = blockIdx.x >> 2;
    const int q  = blockIdx.x & 3;
    const int k0 = q << 6;
    const int lane = t & 63, wave = t >> 6;
    const int wq = wave >> 1, wn = wave & 1;
    const int l31 = lane & 31, l5 = (lane >> 5) & 1;
    const int kcol = (wn << 5) + l31;       // 0..63
    const int kglob = k0 + kcol;

    if (t < 128) diffv[t] = xhat[b * 128 + t] - x[b * 128 + t];

    // ---- init z-state C-fragments from z0 + u (f32, no LDS) ----
    // C/D map: d = 32*mi + 8*rg + 4*l5 + j for reg 4*rg+j, col = kcol.
    f32x16 zs[2], zb[2];
    {
        const float* zr = z0 + kglob * 128;
        const float* ur = u + b * 128;
#pragma unroll
        for (int miL = 0; miL < 2; ++miL) {
            const int mi = 2 * wq + miL;
#pragma unroll
            for (int rg = 0; rg < 4; ++rg) {
                int d0 = 32 * mi + 8 * rg + 4 * l5;
                float4 a = *(const float4*)(zr + d0);
                float4 c = *(const float4*)(ur + d0);
                zs[miL][4*rg+0] = a.x + c.x;
                zs[miL][4*rg+1] = a.y + c.y;
                zs[miL][4*rg+2] = a.z + c.z;
                zs[miL][4*rg+3] = a.w + c.w;
                zb[miL][4*rg+0] = 0.f; zb[miL][4*rg+1] = 0.f;
                zb[miL][4*rg+2] = 0.f; zb[miL][4*rg+3] = 0.f;
            }
        }
    }

    // ---- blk0 GEMM2: zs/zb += W2_0 . relu(H1pre[k] + U1[b])^T  (no LDS, no barriers) ----
    {
        const float* hr = H1pre + kglob * 256;
        const float* ur = U1 + b * 256;
        const uint4* p0base = W2f0 + (2 * wq + 0) * 16 * 128;
        const uint4* p1base = W2f0 + (2 * wq + 1) * 16 * 128;
#pragma unroll 2
        for (int kt = 0; kt < 16; ++kt) {
            const int h0 = 16 * kt + 8 * l5;
            float4 pa = *(const float4*)(hr + h0);
            float4 pb = *(const float4*)(hr + h0 + 4);
            float4 qa = *(const float4*)(ur + h0);
            float4 qb = *(const float4*)(ur + h0 + 4);
            float v0 = fmaxf(pa.x + qa.x, 0.f), v1 = fmaxf(pa.y + qa.y, 0.f);
            float v2 = fmaxf(pa.z + qa.z, 0.f), v3 = fmaxf(pa.w + qa.w, 0.f);
            float v4 = fmaxf(pb.x + qb.x, 0.f), v5 = fmaxf(pb.y + qb.y, 0.f);
            float v6 = fmaxf(pb.z + qb.z, 0.f), v7 = fmaxf(pb.w + qb.w, 0.f);
            uint4 bh, bl;
            bh.x = packhi(v0, v1); bh.y = packhi(v2, v3);
            bh.z = packhi(v4, v5); bh.w = packhi(v6, v7);
            bl.x = packhi(tres(v0), tres(v1)); bl.y = packhi(tres(v2), tres(v3));
            bl.z = packhi(tres(v4), tres(v5)); bl.w = packhi(tres(v6), tres(v7));
            const uint4* p0 = p0base + kt * 128;
            const uint4* p1 = p1base + kt * 128;
            uint4 ah0 = p0[lane], al0 = p0[64 + lane];
            uint4 ah1 = p1[lane], al1 = p1[64 + lane];
            zs[0] = mfma_bf(ah0, bh, zs[0]);
            zb[0] = mfma_bf(ah0, bl, zb[0]);
            zb[0] = mfma_bf(al0, bh, zb[0]);
            zs[1] = mfma_bf(ah1, bh, zs[1]);
            zb[1] = mfma_bf(ah1, bl, zb[1]);
            zb[1] = mfma_bf(al1, bh, zb[1]);
        }
    }

    // ---- fold zb into zs; write split Z to LDS for blk1 GEMM1 ----
#pragma unroll
    for (int miL = 0; miL < 2; ++miL) {
        const int mi = 2 * wq + miL;
#pragma unroll
        for (int rg = 0; rg < 4; ++rg) {
            int d0 = 32 * mi + 8 * rg + 4 * l5;
            float v0 = zs[miL][4*rg+0] + zb[miL][4*rg+0];
            float v1 = zs[miL][4*rg+1] + zb[miL][4*rg+1];
            float v2 = zs[miL][4*rg+2] + zb[miL][4*rg+2];
            float v3 = zs[miL][4*rg+3] + zb[miL][4*rg+3];
            zs[miL][4*rg+0] = v0; zs[miL][4*rg+1] = v1;
            zs[miL][4*rg+2] = v2; zs[miL][4*rg+3] = v3;
            zb[miL][4*rg+0] = 0.f; zb[miL][4*rg+1] = 0.f;
            zb[miL][4*rg+2] = 0.f; zb[miL][4*rg+3] = 0.f;
            uint2 hv, lv;
            hv.x = packhi(v0, v1); hv.y = packhi(v2, v3);
            lv.x = packhi(tres(v0), tres(v1)); lv.y = packhi(tres(v2), tres(v3));
            *(uint2*)&Zh[kcol][d0] = hv;
            *(uint2*)&Zl[kcol][d0] = lv;
        }
    }
    __syncthreads();

    // ---- blk1: 4 chunks of 64 h ----
#pragma unroll 1
    for (int c = 0; c < 4; ++c) {
        if (c > 0) __syncthreads();      // protect H from previous chunk's readers
        // GEMM1: wave does mtile mt = 2c+wq (h rows [32*mt, +32)), both split chains
        f32x16 ach, acl;
#pragma unroll
        for (int r = 0; r < 16; ++r) { ach[r] = 0.f; acl[r] = 0.f; }
        {
            const uint4* pw = W1f1 + (2 * c + wq) * 8 * 128;
#pragma unroll
            for (int kt = 0; kt < 8; ++kt) {
                uint4 bh = *(const uint4*)&Zh[kcol][16 * kt + 8 * l5];
                uint4 bl = *(const uint4*)&Zl[kcol][16 * kt + 8 * l5];
                uint4 ah = pw[kt * 128 + lane];
                uint4 al = pw[kt * 128 + 64 + lane];
                ach = mfma_bf(ah, bh, ach);
                acl = mfma_bf(ah, bl, acl);
                acl = mfma_bf(al, bh, acl);
            }
        }
        // relu + split + store H chunk (local h = 32*wq + 8*rg + 4*l5 + j)
#pragma unroll
        for (int rg = 0; rg < 4; ++rg) {
            int hl0 = 32 * wq + 8 * rg + 4 * l5;
            float v0 = fmaxf(ach[4*rg+0] + acl[4*rg+0], 0.f);
            float v1 = fmaxf(ach[4*rg+1] + acl[4*rg+1], 0.f);
            float v2 = fmaxf(ach[4*rg+2] + acl[4*rg+2], 0.f);
            float v3 = fmaxf(ach[4*rg+3] + acl[4*rg+3], 0.f);
            uint2 hv, lv;
            hv.x = packhi(v0, v1); hv.y = packhi(v2, v3);
            lv.x = packhi(tres(v0), tres(v1)); lv.y = packhi(tres(v2), tres(v3));
            *(uint2*)&Hh[kcol][hl0] = hv;
            *(uint2*)&Hl[kcol][hl0] = lv;
        }
        __syncthreads();
        // GEMM2: zs/zb += W2_1 . hT_chunk
        {
            const uint4* p0base = W2f1 + (2 * wq + 0) * 16 * 128;
            const uint4* p1base = W2f1 + (2 * wq + 1) * 16 * 128;
#pragma unroll
            for (int ktl = 0; ktl < 4; ++ktl) {
                const int hh0 = 16 * ktl + 8 * l5;
                uint4 bh = *(const uint4*)&Hh[kcol][hh0];
                uint4 bl = *(const uint4*)&Hl[kcol][hh0];
                const int ktg = 4 * c + ktl;
                const uint4* p0 = p0base + ktg * 128;
                const uint4* p1 = p1base + ktg * 128;
                uint4 ah0 = p0[lane], al0 = p0[64 + lane];
                uint4 ah1 = p1[lane], al1 = p1[64 + lane];
                zs[0] = mfma_bf(ah0, bh, zs[0]);
                zb[0] = mfma_bf(ah0, bl, zb[0]);
                zb[0] = mfma_bf(al0, bh, zb[0]);
                zs[1] = mfma_bf(ah1, bh, zs[1]);
                zb[1] = mfma_bf(ah1, bl, zb[1]);
                zb[1] = mfma_bf(al1, bh, zb[1]);
            }
        }
    }

    // ---- dist + per-wg argmin over 64 codes ----
    float s = 0.f;
#pragma unroll
    for (int miL = 0; miL < 2; ++miL) {
        const int mi = 2 * wq + miL;
#pragma unroll
        for (int rg = 0; rg < 4; ++rg) {
            int d0 = 32 * mi + 8 * rg + 4 * l5;
            float4 dv = *(const float4*)&diffv[d0];
            float v;
            v = zs[miL][4*rg+0] + zb[miL][4*rg+0] + dv.x; s = fmaf(v, v, s);
            v = zs[miL][4*rg+1] + zb[miL][4*rg+1] + dv.y; s = fmaf(v, v, s);
            v = zs[miL][4*rg+2] + zb[miL][4*rg+2] + dv.z; s = fmaf(v, v, s);
            v = zs[miL][4*rg+3] + zb[miL][4*rg+3] + dv.w; s = fmaf(v, v, s);
        }
    }
    s += __shfl_xor(s, 32, 64);          // combine l5 halves (same kcol)
    if (l5 == 0) red[wq][kcol] = s;
    __syncthreads();
    if (wave == 0) {
        float v = red[0][lane] + red[1][lane];
        int idx = lane;
#pragma unroll
        for (int off = 32; off > 0; off >>= 1) {
            float ov = __shfl_xor(v, off, 64);
            int oi = __shfl_xor(idx, off, 64);
            if (ov < v || (ov == v && oi < idx)) { v = ov; idx = oi; }
        }
        if (lane == 0) wsmin[b * 4 + q] = make_float2(v, (float)(k0 + idx));
    }
}

// ---------------- final argmin over 4 quads ----------------
__global__ __launch_bounds__(256) void k_argmin2(
    const float2* __restrict__ wsmin, int* __restrict__ codes,
    float* __restrict__ out0)
{
    int b = blockIdx.x * 256 + threadIdx.x;   // grid 8 -> 2048
    float2 m = wsmin[b * 4];
    float bv = m.x, bi = m.y;
#pragma unroll
    for (int qq = 1; qq < 4; ++qq) {
        float2 c = wsmin[b * 4 + qq];
        if (c.x < bv) { bv = c.x; bi = c.y; }   // strict <: ties keep lowest k
    }
    codes[b] = (int)bi;
    out0[b] = bi;
}

// ---------------- winner recompute (f32-exact) ----------------
__global__ __launch_bounds__(256) void k_final(
    const float* __restrict__ z0, const float* __restrict__ u,
    const int* __restrict__ codes,
    const float* __restrict__ W1Ta, const float* __restrict__ W2Ta,
    const float* __restrict__ W1Tb, const float* __restrict__ W2Tb,
    float* __restrict__ outd)
{
    __shared__ float z8[8][128];
    __shared__ float h8[8][256];
    __shared__ int ci[8];
    const int t = threadIdx.x;
    const int b0 = blockIdx.x * 8;
    if (t < 8) ci[t] = codes[b0 + t];
    __syncthreads();
#pragma unroll
    for (int n = 0; n < 4; ++n) {
        int e = n * 256 + t; int r = e >> 7, d = e & 127;
        z8[r][d] = z0[ci[r] * 128 + d] + u[(b0 + r) * 128 + d];
    }
    __syncthreads();
    const float* W1T = W1Ta; const float* W2T = W2Ta;
#pragma unroll 1
    for (int blk = 0; blk < 2; ++blk) {
        float a1[8] = {0.f,0.f,0.f,0.f,0.f,0.f,0.f,0.f};
        for (int d = 0; d < 128; ++d) {
            const float w = W1T[d * 256 + t];
#pragma unroll
            for (int r = 0; r < 8; ++r) a1[r] = fmaf(z8[r][d], w, a1[r]);
        }
#pragma unroll
        for (int r = 0; r < 8; ++r) h8[r][t] = fmaxf(a1[r], 0.f);
        __syncthreads();
        const int ig = t & 127, rg = (t >> 7) * 4;
        float a2[4] = {0.f,0.f,0.f,0.f};
        for (int h = 0; h < 256; ++h) {
            const float w = W2T[h * 128 + ig];
#pragma unroll
            for (int j = 0; j < 4; ++j) a2[j] = fmaf(h8[rg + j][h], w, a2[j]);
        }
        __syncthreads();
#pragma unroll
        for (int j = 0; j < 4; ++j) z8[rg + j][ig] += a2[j];
        __syncthreads();
        W1T = W1Tb; W2T = W2Tb;
    }
#pragma unroll
    for (int n = 0; n < 4; ++n) {
        int e = n * 256 + t; int r = e >> 7, d = e & 127;
        outd[(b0 + r) * 128 + d] = z8[r][d];
    }
}

extern "C" void kernel_launch(void* const* d_in, const int* in_sizes, int n_in,
                              void* d_out, int out_size, void* d_ws, size_t ws_size,
                              hipStream_t stream) {
    const float* xhat = (const float*)d_in[0];
    const float* x    = (const float*)d_in[1];
    const float* cb   = (const float*)d_in[2];
    const float* Wc   = (const float*)d_in[3];
    const float* bc   = (const float*)d_in[4];
    const float* W1_0 = (const float*)d_in[5];
    const float* W2_0 = (const float*)d_in[6];
    const float* W1_1 = (const float*)d_in[7];
    const float* W2_1 = (const float*)d_in[8];
    float* out = (float*)d_out;
    float* ws  = (float*)d_ws;

    float* WzT   = ws + 0;
    float* WxT   = ws + 16384;
    float* W1T0  = ws + 32768;
    float* W2T0  = ws + 65536;
    float* W1T1  = ws + 98304;
    float* W2T1  = ws + 131072;
    float* z0    = ws + 163840;
    float* u     = ws + 196608;
    float* H1pre = ws + 458752;
    float* U1    = ws + 524288;
    float2* wsmin = (float2*)(ws + 1048576);
    int*   codes = (int*)(ws + 1064960);
    uint4* F     = (uint4*)(ws + 1067008);   // 32768 uint4 = 512 KB
    const uint4* W2f0 = F + 8192;
    const uint4* W1f1 = F + 16384;
    const uint4* W2f1 = F + 24576;

    k_transpose<<<640, 256, 0, stream>>>(Wc, W1_0, W2_0, W1_1, W2_1,
                                         WzT, WxT, W1T0, W2T0, W1T1, W2T1);
    k_pack<<<64, 256, 0, stream>>>(W1_0, W2_0, W1_1, W2_1, F);
    k_z0<<<128, 256, 0, stream>>>(cb, bc, WzT, z0);
    k_u<<<1024, 256, 0, stream>>>(xhat, WxT, u);
    k_preh<<<64, 256, 0, stream>>>(z0, W1_0, H1pre);     // H1pre[k] = W1_0 . z0[k]
    k_preh<<<512, 256, 0, stream>>>(u, W1_0, U1);        // U1[b]   = W1_0 . u[b]
    k_dist_mfma<<<8192, 256, 0, stream>>>(z0, u, xhat, x, H1pre, U1,
                                          W2f0, W1f1, W2f1, wsmin);
    k_argmin2<<<8, 256, 0, stream>>>(wsmin, codes, out);
    k_final<<<256, 256, 0, stream>>>(z0, u, codes, W1T0, W2T0, W1T1, W2T1, out + 2048);
}

// Round 4
// 551.762 us; speedup vs baseline: 1.1164x; 1.1164x over previous
//
#include <hip/hip_runtime.h>

// QINCoStep — bs=2048, d=128, K=256, h=256, fp32 in/out.
// Round 4: L2-byte-bound fix. wg = 512 thr / 8 waves covers 1 b x 128 codes.
// All activation operands flow through LDS in MFMA-fragment order; weights
// amortized over 4 colgroups per wg; r0 (= relu(H1pre[k]+U1[b])) staged
// cooperatively so H1pre is read exactly once per wg.
//
// ws layout (floats):
//   0       WzT   16384      16384  WxT   16384
//   32768   W1T0  32768      65536  W2T0  32768
//   98304   W1T1  32768      131072 W2T1  32768
//   163840  z0    32768      196608 u     262144
//   458752  H1pre 65536      524288 U1    524288
//   1048576 wsmin (2048*2 float2)
//   1064960 codes 2048 (int)
//   1067008 frag region F: 32768 uint4 (512 KB)

typedef short bf8_t __attribute__((ext_vector_type(8)));
typedef float f32x16 __attribute__((ext_vector_type(16)));

__device__ inline unsigned short f2bh(float x) {
    unsigned u = __float_as_uint(x);
    u += 0x7fffu + ((u >> 16) & 1u);
    return (unsigned short)(u >> 16);
}
__device__ inline float bh2f(unsigned short h) {
    return __uint_as_float(((unsigned)h) << 16);
}
__device__ inline f32x16 mfma_bf(uint4 a, uint4 b, f32x16 c) {
    bf8_t av = __builtin_bit_cast(bf8_t, a);
    bf8_t bv = __builtin_bit_cast(bf8_t, b);
    return __builtin_amdgcn_mfma_f32_32x32x16_bf16(av, bv, c, 0, 0, 0);
}
// pack hi16(x) into low half, hi16(y) into high half (1 v_perm_b32)
__device__ inline unsigned packhi(float x, float y) {
    return __builtin_amdgcn_perm(__float_as_uint(y), __float_as_uint(x), 0x07060302u);
}
__device__ inline float tres(float v) {   // exact residual of bf16-truncation
    return v - __uint_as_float(__float_as_uint(v) & 0xFFFF0000u);
}

// ---------------- prep kernels ----------------

__global__ __launch_bounds__(256) void k_transpose(
    const float* __restrict__ Wc,
    const float* __restrict__ W1a, const float* __restrict__ W2a,
    const float* __restrict__ W1b, const float* __restrict__ W2b,
    float* __restrict__ WzT, float* __restrict__ WxT,
    float* __restrict__ W1Ta, float* __restrict__ W2Ta,
    float* __restrict__ W1Tb, float* __restrict__ W2Tb)
{
    int g = blockIdx.x * 256 + threadIdx.x;   // 0 .. 163839
    if (g < 16384) {
        int j = g >> 7, d = g & 127;
        WzT[g] = Wc[d * 256 + j];
    } else if (g < 32768) {
        int e = g - 16384; int j = e >> 7, d = e & 127;
        WxT[e] = Wc[d * 256 + 128 + j];
    } else if (g < 65536) {
        int e = g - 32768; int d = e >> 8, h = e & 255;
        W1Ta[e] = W1a[h * 128 + d];
    } else if (g < 98304) {
        int e = g - 65536; int h = e >> 7, i = e & 127;
        W2Ta[e] = W2a[i * 256 + h];
    } else if (g < 131072) {
        int e = g - 98304; int d = e >> 8, h = e & 255;
        W1Tb[e] = W1b[h * 128 + d];
    } else if (g < 163840) {
        int e = g - 131072; int h = e >> 7, i = e & 127;
        W2Tb[e] = W2b[i * 256 + h];
    }
}

// Pack weights into A-fragments (hi/lo bf16, RNE) for mfma 32x32x16.
// lane -> row m = 32*mt + (lane&31), cols 16*kt + 8*(lane>>5) + j.
__global__ __launch_bounds__(256) void k_pack(
    const float* __restrict__ W1a, const float* __restrict__ W2a,
    const float* __restrict__ W1b, const float* __restrict__ W2b,
    uint4* __restrict__ F)
{
    int idx = blockIdx.x * 256 + threadIdx.x;   // 0..16383
    int mat = idx >> 12, fp = idx & 4095;
    int tile = fp >> 6, lane = fp & 63;
    const float* src;
    if (mat == 0 || mat == 2) {                 // W1-type: [256][128], 8 mt x 8 kt
        const float* W = (mat == 0) ? W1a : W1b;
        int mt = tile >> 3, kt = tile & 7;
        int m = 32 * mt + (lane & 31);
        int c0 = 16 * kt + 8 * ((lane >> 5) & 1);
        src = W + m * 128 + c0;
    } else {                                    // W2-type: [128][256], 4 mt x 16 kt
        const float* W = (mat == 1) ? W2a : W2b;
        int mt = tile >> 4, kt = tile & 15;
        int m = 32 * mt + (lane & 31);
        int c0 = 16 * kt + 8 * ((lane >> 5) & 1);
        src = W + m * 256 + c0;
    }
    unsigned short hs[8], ls[8];
#pragma unroll
    for (int j = 0; j < 8; ++j) {
        float v = src[j];
        unsigned short h = f2bh(v);
        hs[j] = h;
        ls[j] = f2bh(v - bh2f(h));
    }
    uint4 hv, lv;
    hv.x = (unsigned)hs[0] | ((unsigned)hs[1] << 16);
    hv.y = (unsigned)hs[2] | ((unsigned)hs[3] << 16);
    hv.z = (unsigned)hs[4] | ((unsigned)hs[5] << 16);
    hv.w = (unsigned)hs[6] | ((unsigned)hs[7] << 16);
    lv.x = (unsigned)ls[0] | ((unsigned)ls[1] << 16);
    lv.y = (unsigned)ls[2] | ((unsigned)ls[3] << 16);
    lv.z = (unsigned)ls[4] | ((unsigned)ls[5] << 16);
    lv.w = (unsigned)ls[6] | ((unsigned)ls[7] << 16);
    uint4* dst = F + mat * 8192 + tile * 128;
    dst[lane] = hv;
    dst[64 + lane] = lv;
}

__global__ __launch_bounds__(256) void k_z0(
    const float* __restrict__ cb, const float* __restrict__ bc,
    const float* __restrict__ WzT, float* __restrict__ z0)
{
    int g = blockIdx.x * 256 + threadIdx.x;   // 0..32767
    int k = g >> 7, d = g & 127;
    float acc = bc[d] + cb[k * 128 + d];
    for (int j = 0; j < 128; ++j)
        acc = fmaf(cb[k * 128 + j], WzT[j * 128 + d], acc);
    z0[g] = acc;
}

__global__ __launch_bounds__(256) void k_u(
    const float* __restrict__ xhat, const float* __restrict__ WxT,
    float* __restrict__ u)
{
    int g = blockIdx.x * 256 + threadIdx.x;   // 0..262143
    int bl = g >> 7, d = g & 127;
    const float* xr = xhat + bl * 128;
    float acc = 0.f;
    for (int j = 0; j < 128; ++j)
        acc = fmaf(xr[j], WxT[j * 128 + d], acc);
    u[g] = acc;
}

// dst[r][h] = sum_i src[r][i] * W1[h][i]; 4 rows per workgroup, thread = h.
__global__ __launch_bounds__(256) void k_preh(
    const float* __restrict__ src, const float* __restrict__ W1,
    float* __restrict__ dst)
{
    __shared__ float s[4][128];
    const int t = threadIdx.x;
    const int r0 = blockIdx.x * 4;
#pragma unroll
    for (int e = t; e < 512; e += 256)
        s[e >> 7][e & 127] = src[(r0 + (e >> 7)) * 128 + (e & 127)];
    __syncthreads();
    float a0 = 0.f, a1 = 0.f, a2 = 0.f, a3 = 0.f;
    const float* wr = W1 + t * 128;
    for (int i = 0; i < 128; i += 4) {
        float4 w = *(const float4*)(wr + i);
        a0 = fmaf(s[0][i], w.x, fmaf(s[0][i+1], w.y, fmaf(s[0][i+2], w.z, fmaf(s[0][i+3], w.w, a0))));
        a1 = fmaf(s[1][i], w.x, fmaf(s[1][i+1], w.y, fmaf(s[1][i+2], w.z, fmaf(s[1][i+3], w.w, a1))));
        a2 = fmaf(s[2][i], w.x, fmaf(s[2][i+1], w.y, fmaf(s[2][i+2], w.z, fmaf(s[2][i+3], w.w, a2))));
        a3 = fmaf(s[3][i], w.x, fmaf(s[3][i+1], w.y, fmaf(s[3][i+2], w.z, fmaf(s[3][i+3], w.w, a3))));
    }
    dst[(r0 + 0) * 256 + t] = a0;
    dst[(r0 + 1) * 256 + t] = a1;
    dst[(r0 + 2) * 256 + t] = a2;
    dst[(r0 + 3) * 256 + t] = a3;
}

// ---------------- main MFMA dist kernel ----------------
// 512 threads / 8 waves; wg = (b, 128-code half q). wave = (wm = wave&3, wn = wave>>2).
// Accumulator zs/zb: mi=1 (d-tile wm) x cg=2 (colgroups {2wn, 2wn+1}).
// Fragment block in LDS = 128 uint4: [0..63] hi (uint4 per consuming lane),
// [64..127] lo. Zf: (g*8 + kt) blocks (kt over d). Hf: (g*4 + ktl) blocks.
__global__ __launch_bounds__(512) void k_dist_mfma(
    const float* __restrict__ z0, const float* __restrict__ u,
    const float* __restrict__ xhat, const float* __restrict__ x,
    const float* __restrict__ H1pre, const float* __restrict__ U1,
    const uint4* __restrict__ W2f0, const uint4* __restrict__ W1f1,
    const uint4* __restrict__ W2f1, float2* __restrict__ wsmin)
{
    __shared__ uint4 Zf[4096];   // 64 KB: Z frags, 4 g x 8 kt
    __shared__ uint4 Hf[2048];   // 32 KB: r0 / H-chunk frags, 4 g x 4 ktl (union: red/distb at end)

    const int t = threadIdx.x;
    const int lane = t & 63, wave = t >> 6;
    const int wm = wave & 3, wn = wave >> 2;
    const int l31 = lane & 31, l5 = lane >> 5;
    const int b = blockIdx.x >> 1, q = blockIdx.x & 1;
    const int k0 = q << 7;

    // ---- P0: init zs = z0[k] + u[b] at C-frag positions ----
    f32x16 zs[2], zb[2];
    {
        const float* ub = u + b * 128;
#pragma unroll
        for (int g = 0; g < 2; ++g) {
            const int colw = ((wn << 1) + g) * 32 + l31;
            const float* zr = z0 + (k0 + colw) * 128;
#pragma unroll
            for (int rg = 0; rg < 4; ++rg) {
                const int d0 = 32 * wm + 8 * rg + 4 * l5;
                float4 a = *(const float4*)(zr + d0);
                float4 c = *(const float4*)(ub + d0);
                zs[g][4*rg+0] = a.x + c.x; zs[g][4*rg+1] = a.y + c.y;
                zs[g][4*rg+2] = a.z + c.z; zs[g][4*rg+3] = a.w + c.w;
                zb[g][4*rg+0] = 0.f; zb[g][4*rg+1] = 0.f;
                zb[g][4*rg+2] = 0.f; zb[g][4*rg+3] = 0.f;
            }
        }
    }

    // ---- P0b: blk0-G2 (z += W2_0 . r0^T) in 4 rounds of 4 kt ----
#pragma unroll 1
    for (int r = 0; r < 4; ++r) {
        {   // stage r0 frags: this wave builds kt = 4r+wm for col = 64*wn + lane
            const int kt = 4 * r + wm;
            const int colw = 64 * wn + lane;
            const float* hr = H1pre + (k0 + colw) * 256 + 16 * kt;
            const float* ur = U1 + b * 256 + 16 * kt;
            float v[16];
#pragma unroll
            for (int i = 0; i < 16; i += 4) {
                float4 hp = *(const float4*)(hr + i);
                float4 up = *(const float4*)(ur + i);
                v[i+0] = fmaxf(hp.x + up.x, 0.f);
                v[i+1] = fmaxf(hp.y + up.y, 0.f);
                v[i+2] = fmaxf(hp.z + up.z, 0.f);
                v[i+3] = fmaxf(hp.w + up.w, 0.f);
            }
            uint4 h0, h1, lo0, lo1;
            h0.x = packhi(v[0], v[1]);   h0.y = packhi(v[2], v[3]);
            h0.z = packhi(v[4], v[5]);   h0.w = packhi(v[6], v[7]);
            h1.x = packhi(v[8], v[9]);   h1.y = packhi(v[10], v[11]);
            h1.z = packhi(v[12], v[13]); h1.w = packhi(v[14], v[15]);
            lo0.x = packhi(tres(v[0]), tres(v[1]));   lo0.y = packhi(tres(v[2]), tres(v[3]));
            lo0.z = packhi(tres(v[4]), tres(v[5]));   lo0.w = packhi(tres(v[6]), tres(v[7]));
            lo1.x = packhi(tres(v[8]), tres(v[9]));   lo1.y = packhi(tres(v[10]), tres(v[11]));
            lo1.z = packhi(tres(v[12]), tres(v[13])); lo1.w = packhi(tres(v[14]), tres(v[15]));
            uint4* base = &Hf[((((wn << 1) + l5) << 2) + wm) * 128];
            base[l31]      = h0;   // l5'=0 consuming lanes
            base[32 + l31] = h1;   // l5'=1
            base[64 + l31] = lo0;
            base[96 + l31] = lo1;
        }
        __syncthreads();
        // MFMA sweep over the 4 staged kt
#pragma unroll
        for (int ktl = 0; ktl < 4; ++ktl) {
            const int kt = 4 * r + ktl;
            const uint4* pa = W2f0 + (wm * 16 + kt) * 128;
            uint4 ah = pa[lane], al = pa[64 + lane];
#pragma unroll
            for (int g = 0; g < 2; ++g) {
                const uint4* pb = &Hf[((((wn << 1) + g) << 2) + ktl) * 128];
                uint4 bh = pb[lane], bl = pb[64 + lane];
                zs[g] = mfma_bf(ah, bh, zs[g]);
                zb[g] = mfma_bf(ah, bl, zb[g]);
                zb[g] = mfma_bf(al, bh, zb[g]);
            }
        }
        __syncthreads();
    }

    // ---- P1: fold zb into zs; write split z1 to Zf (fragment order) ----
#pragma unroll
    for (int g = 0; g < 2; ++g) {
#pragma unroll
        for (int rg = 0; rg < 4; ++rg) {
            float v0 = zs[g][4*rg+0] + zb[g][4*rg+0];
            float v1 = zs[g][4*rg+1] + zb[g][4*rg+1];
            float v2 = zs[g][4*rg+2] + zb[g][4*rg+2];
            float v3 = zs[g][4*rg+3] + zb[g][4*rg+3];
            zs[g][4*rg+0] = v0; zs[g][4*rg+1] = v1;
            zs[g][4*rg+2] = v2; zs[g][4*rg+3] = v3;
            zb[g][4*rg+0] = 0.f; zb[g][4*rg+1] = 0.f;
            zb[g][4*rg+2] = 0.f; zb[g][4*rg+3] = 0.f;
            uint2 hi, lo;
            hi.x = packhi(v0, v1); hi.y = packhi(v2, v3);
            lo.x = packhi(tres(v0), tres(v1)); lo.y = packhi(tres(v2), tres(v3));
            // d = 32wm + 8rg + 4l5 + j  ->  kt = 2wm + (rg>>1), l5' = rg&1, j' = 4l5+j
            uint2* zb2 = (uint2*)&Zf[((((wn << 1) + g) << 3) + 2 * wm + (rg >> 1)) * 128];
            const int cl = ((rg & 1) << 5) + l31;
            zb2[cl * 2 + l5]       = hi;
            zb2[128 + cl * 2 + l5] = lo;
        }
    }
    __syncthreads();

    // ---- P2: blk1 in 4 chunks of 64 h ----
    const int gG1 = (wn << 1) + (wm >> 1);   // this wave's G1 colgroup
#pragma unroll 1
    for (int c = 0; c < 4; ++c) {
        // G1: h-tile 2c + (wm&1), colgroup gG1, dual split chains
        f32x16 ha, hb;
#pragma unroll
        for (int rr = 0; rr < 16; ++rr) { ha[rr] = 0.f; hb[rr] = 0.f; }
        {
            const uint4* pw1 = W1f1 + ((2 * c + (wm & 1)) * 8) * 128;
#pragma unroll
            for (int kt = 0; kt < 8; ++kt) {
                const uint4* pb = &Zf[((gG1 << 3) + kt) * 128];
                uint4 bh = pb[lane], bl = pb[64 + lane];
                const uint4* pa = pw1 + kt * 128;
                uint4 ah = pa[lane], al = pa[64 + lane];
                ha = mfma_bf(ah, bh, ha);
                hb = mfma_bf(ah, bl, hb);
                hb = mfma_bf(al, bh, hb);
            }
        }
        __syncthreads();   // previous chunk's Hf readers done
        // relu + split + write H frags (chunk-local h = 32*(wm&1) + 8rg + 4l5 + j)
#pragma unroll
        for (int rg = 0; rg < 4; ++rg) {
            float v0 = fmaxf(ha[4*rg+0] + hb[4*rg+0], 0.f);
            float v1 = fmaxf(ha[4*rg+1] + hb[4*rg+1], 0.f);
            float v2 = fmaxf(ha[4*rg+2] + hb[4*rg+2], 0.f);
            float v3 = fmaxf(ha[4*rg+3] + hb[4*rg+3], 0.f);
            uint2 hi, lo;
            hi.x = packhi(v0, v1); hi.y = packhi(v2, v3);
            lo.x = packhi(tres(v0), tres(v1)); lo.y = packhi(tres(v2), tres(v3));
            uint2* hb2 = (uint2*)&Hf[((gG1 << 2) + ((wm & 1) << 1) + (rg >> 1)) * 128];
            const int cl = ((rg & 1) << 5) + l31;
            hb2[cl * 2 + l5]       = hi;
            hb2[128 + cl * 2 + l5] = lo;
        }
        __syncthreads();
        // G2: zs/zb += W2_1[d-tile wm] . H_chunk
#pragma unroll
        for (int ktl = 0; ktl < 4; ++ktl) {
            const uint4* pa = W2f1 + (wm * 16 + 4 * c + ktl) * 128;
            uint4 ah = pa[lane], al = pa[64 + lane];
#pragma unroll
            for (int g = 0; g < 2; ++g) {
                const uint4* pb = &Hf[((((wn << 1) + g) << 2) + ktl) * 128];
                uint4 bh = pb[lane], bl = pb[64 + lane];
                zs[g] = mfma_bf(ah, bh, zs[g]);
                zb[g] = mfma_bf(ah, bl, zb[g]);
                zb[g] = mfma_bf(al, bh, zb[g]);
            }
        }
    }

    // ---- P3: dist + argmin over this wg's 128 codes ----
    float* red   = (float*)Hf;         // [4][128]
    float* distb = (float*)Hf + 512;   // [128]
    __syncthreads();                   // all Hf MFMA readers done
#pragma unroll
    for (int g = 0; g < 2; ++g) {
        float s = 0.f;
        const int colw = ((wn << 1) + g) * 32 + l31;
#pragma unroll
        for (int rg = 0; rg < 4; ++rg) {
            const int d0 = 32 * wm + 8 * rg + 4 * l5;
            float4 xh = *(const float4*)(xhat + b * 128 + d0);
            float4 xx = *(const float4*)(x + b * 128 + d0);
            float v;
            v = zs[g][4*rg+0] + zb[g][4*rg+0] + (xh.x - xx.x); s = fmaf(v, v, s);
            v = zs[g][4*rg+1] + zb[g][4*rg+1] + (xh.y - xx.y); s = fmaf(v, v, s);
            v = zs[g][4*rg+2] + zb[g][4*rg+2] + (xh.z - xx.z); s = fmaf(v, v, s);
            v = zs[g][4*rg+3] + zb[g][4*rg+3] + (xh.w - xx.w); s = fmaf(v, v, s);
        }
        s += __shfl_xor(s, 32, 64);    // pair lane has same col, other l5 half
        if (l5 == 0) red[wm * 128 + colw] = s;
    }
    __syncthreads();
    if (t < 128)
        distb[t] = red[t] + red[128 + t] + red[256 + t] + red[384 + t];
    __syncthreads();
    if (wave == 0) {
        float v0 = distb[lane], v1 = distb[lane + 64];
        float v; int idx;
        if (v1 < v0) { v = v1; idx = lane + 64; } else { v = v0; idx = lane; }
#pragma unroll
        for (int off = 32; off > 0; off >>= 1) {
            float ov = __shfl_xor(v, off, 64);
            int oi = __shfl_xor(idx, off, 64);
            if (ov < v || (ov == v && oi < idx)) { v = ov; idx = oi; }
        }
        if (lane == 0) wsmin[b * 2 + q] = make_float2(v, (float)(k0 + idx));
    }
}

// ---------------- final argmin over the 2 halves ----------------
__global__ __launch_bounds__(256) void k_argmin2(
    const float2* __restrict__ wsmin, int* __restrict__ codes,
    float* __restrict__ out0)
{
    int b = blockIdx.x * 256 + threadIdx.x;   // grid 8 -> 2048
    float2 m0 = wsmin[b * 2];
    float2 m1 = wsmin[b * 2 + 1];
    float bv = m0.x, bi = m0.y;
    if (m1.x < bv) { bv = m1.x; bi = m1.y; }  // strict <: ties keep lower k
    codes[b] = (int)bi;
    out0[b] = bi;
}

// ---------------- winner recompute (f32-exact) ----------------
__global__ __launch_bounds__(256) void k_final(
    const float* __restrict__ z0, const float* __restrict__ u,
    const int* __restrict__ codes,
    const float* __restrict__ W1Ta, const float* __restrict__ W2Ta,
    const float* __restrict__ W1Tb, const float* __restrict__ W2Tb,
    float* __restrict__ outd)
{
    __shared__ float z8[8][128];
    __shared__ float h8[8][256];
    __shared__ int ci[8];
    const int t = threadIdx.x;
    const int b0 = blockIdx.x * 8;
    if (t < 8) ci[t] = codes[b0 + t];
    __syncthreads();
#pragma unroll
    for (int n = 0; n < 4; ++n) {
        int e = n * 256 + t; int r = e >> 7, d = e & 127;
        z8[r][d] = z0[ci[r] * 128 + d] + u[(b0 + r) * 128 + d];
    }
    __syncthreads();
    const float* W1T = W1Ta; const float* W2T = W2Ta;
#pragma unroll 1
    for (int blk = 0; blk < 2; ++blk) {
        float a1[8] = {0.f,0.f,0.f,0.f,0.f,0.f,0.f,0.f};
        for (int d = 0; d < 128; ++d) {
            const float w = W1T[d * 256 + t];
#pragma unroll
            for (int r = 0; r < 8; ++r) a1[r] = fmaf(z8[r][d], w, a1[r]);
        }
#pragma unroll
        for (int r = 0; r < 8; ++r) h8[r][t] = fmaxf(a1[r], 0.f);
        __syncthreads();
        const int ig = t & 127, rg = (t >> 7) * 4;
        float a2[4] = {0.f,0.f,0.f,0.f};
        for (int h = 0; h < 256; ++h) {
            const float w = W2T[h * 128 + ig];
#pragma unroll
            for (int j = 0; j < 4; ++j) a2[j] = fmaf(h8[rg + j][h], w, a2[j]);
        }
        __syncthreads();
#pragma unroll
        for (int j = 0; j < 4; ++j) z8[rg + j][ig] += a2[j];
        __syncthreads();
        W1T = W1Tb; W2T = W2Tb;
    }
#pragma unroll
    for (int n = 0; n < 4; ++n) {
        int e = n * 256 + t; int r = e >> 7, d = e & 127;
        outd[(b0 + r) * 128 + d] = z8[r][d];
    }
}

extern "C" void kernel_launch(void* const* d_in, const int* in_sizes, int n_in,
                              void* d_out, int out_size, void* d_ws, size_t ws_size,
                              hipStream_t stream) {
    const float* xhat = (const float*)d_in[0];
    const float* x    = (const float*)d_in[1];
    const float* cb   = (const float*)d_in[2];
    const float* Wc   = (const float*)d_in[3];
    const float* bc   = (const float*)d_in[4];
    const float* W1_0 = (const float*)d_in[5];
    const float* W2_0 = (const float*)d_in[6];
    const float* W1_1 = (const float*)d_in[7];
    const float* W2_1 = (const float*)d_in[8];
    float* out = (float*)d_out;
    float* ws  = (float*)d_ws;

    float* WzT   = ws + 0;
    float* WxT   = ws + 16384;
    float* W1T0  = ws + 32768;
    float* W2T0  = ws + 65536;
    float* W1T1  = ws + 98304;
    float* W2T1  = ws + 131072;
    float* z0    = ws + 163840;
    float* u     = ws + 196608;
    float* H1pre = ws + 458752;
    float* U1    = ws + 524288;
    float2* wsmin = (float2*)(ws + 1048576);
    int*   codes = (int*)(ws + 1064960);
    uint4* F     = (uint4*)(ws + 1067008);   // 32768 uint4 = 512 KB
    const uint4* W2f0 = F + 8192;
    const uint4* W1f1 = F + 16384;
    const uint4* W2f1 = F + 24576;

    k_transpose<<<640, 256, 0, stream>>>(Wc, W1_0, W2_0, W1_1, W2_1,
                                         WzT, WxT, W1T0, W2T0, W1T1, W2T1);
    k_pack<<<64, 256, 0, stream>>>(W1_0, W2_0, W1_1, W2_1, F);
    k_z0<<<128, 256, 0, stream>>>(cb, bc, WzT, z0);
    k_u<<<1024, 256, 0, stream>>>(xhat, WxT, u);
    k_preh<<<64, 256, 0, stream>>>(z0, W1_0, H1pre);     // H1pre[k] = W1_0 . z0[k]
    k_preh<<<512, 256, 0, stream>>>(u, W1_0, U1);        // U1[b]   = W1_0 . u[b]
    k_dist_mfma<<<4096, 512, 0, stream>>>(z0, u, xhat, x, H1pre, U1,
                                          W2f0, W1f1, W2f1, wsmin);
    k_argmin2<<<8, 256, 0, stream>>>(wsmin, codes, out);
    k_final<<<256, 256, 0, stream>>>(z0, u, codes, W1T0, W2T0, W1T1, W2T1, out + 2048);
}

// Round 5
// 347.494 us; speedup vs baseline: 1.7726x; 1.5878x over previous
//
#include <hip/hip_runtime.h>

// QINCoStep — bs=2048, d=128, K=256, h=256, fp32 in/out.
// Round 5: approximate-then-refine.
//  - k_dist_approx: hi-only RNE bf16 MFMA (1 product per pair), 48 KB LDS -> 3 wg/CU
//  - k_select: per-row candidates with approx <= min + DELTA (DELTA=4 >> 2*err_max)
//  - k_exact: exact f32 MLP+dist for ~1.3 cand/row (batched 8/wg)
//  - k_pick + k_final: exact argmin, winner z recompute (f32)
//
// ws layout (floats):
//   0        WzT 16384        16384   WxT 16384
//   32768    W1T0 32768       65536   W2T0 32768
//   98304    W1T1 32768       131072  W2T1 32768
//   163840   z0 32768         196608  u 262144
//   458752   dist 524288
//   983040   z0bf (ushort 32768 = 16384 fl)
//   999424   ubf  (ushort 262144 = 131072 fl)
//   1130496  U1bf (ushort 524288 = 262144 fl)
//   1392640  H1f  (8192 uint4 = 32768 fl)
//   1425408  F    (12288 uint4 = 49152 fl): W2f0, W1f1, W2f1 (4096 uint4 each)
//   1474560  cand_k (int 16384)
//   1490944  cand_cnt (int 2048)
//   1492992  ex_dist (fl 16384)
//   1509376  pairs (int2 16384 = 32768 ints)
//   1542144  npairs (int 1)   1542148 codes (int 2048)

typedef short bf8_t __attribute__((ext_vector_type(8)));
typedef float f32x16 __attribute__((ext_vector_type(16)));

__device__ inline unsigned short f2bh(float x) {   // RNE f32->bf16
    unsigned u = __float_as_uint(x);
    u += 0x7fffu + ((u >> 16) & 1u);
    return (unsigned short)(u >> 16);
}
__device__ inline float bh2f(unsigned short h) {
    return __uint_as_float(((unsigned)h) << 16);
}
__device__ inline f32x16 mfma_bf(uint4 a, uint4 b, f32x16 c) {
    bf8_t av = __builtin_bit_cast(bf8_t, a);
    bf8_t bv = __builtin_bit_cast(bf8_t, b);
    return __builtin_amdgcn_mfma_f32_32x32x16_bf16(av, bv, c, 0, 0, 0);
}
// (bf16pair hv) + (bf16pair uv) -> relu -> RNE bf16pair
__device__ inline unsigned addrelu2(unsigned hv, unsigned uv) {
    float h0 = __uint_as_float(hv << 16), h1 = __uint_as_float(hv & 0xFFFF0000u);
    float u0 = __uint_as_float(uv << 16), u1 = __uint_as_float(uv & 0xFFFF0000u);
    float v0 = fmaxf(h0 + u0, 0.f), v1 = fmaxf(h1 + u1, 0.f);
    return ((unsigned)f2bh(v1) << 16) | (unsigned)f2bh(v0);
}
__device__ inline unsigned pack2(float a, float b) {
    return ((unsigned)f2bh(b) << 16) | (unsigned)f2bh(a);
}

#define DELTA 4.0f

// ---------------- prep kernels ----------------

__global__ __launch_bounds__(256) void k_transpose(
    const float* __restrict__ Wc,
    const float* __restrict__ W1a, const float* __restrict__ W2a,
    const float* __restrict__ W1b, const float* __restrict__ W2b,
    float* __restrict__ WzT, float* __restrict__ WxT,
    float* __restrict__ W1Ta, float* __restrict__ W2Ta,
    float* __restrict__ W1Tb, float* __restrict__ W2Tb)
{
    int g = blockIdx.x * 256 + threadIdx.x;   // 0 .. 163839
    if (g < 16384) {
        int j = g >> 7, d = g & 127;
        WzT[g] = Wc[d * 256 + j];
    } else if (g < 32768) {
        int e = g - 16384; int j = e >> 7, d = e & 127;
        WxT[e] = Wc[d * 256 + 128 + j];
    } else if (g < 65536) {
        int e = g - 32768; int d = e >> 8, h = e & 255;
        W1Ta[e] = W1a[h * 128 + d];
    } else if (g < 98304) {
        int e = g - 65536; int h = e >> 7, i = e & 127;
        W2Ta[e] = W2a[i * 256 + h];
    } else if (g < 131072) {
        int e = g - 98304; int d = e >> 8, h = e & 255;
        W1Tb[e] = W1b[h * 128 + d];
    } else if (g < 163840) {
        int e = g - 131072; int h = e >> 7, i = e & 127;
        W2Tb[e] = W2b[i * 256 + h];
    }
}

// hi-only RNE A-fragments for W2_0 (mat0), W1_1 (mat1), W2_1 (mat2)
__global__ __launch_bounds__(256) void k_pack(
    const float* __restrict__ W2a, const float* __restrict__ W1b,
    const float* __restrict__ W2b, uint4* __restrict__ F)
{
    int idx = blockIdx.x * 256 + threadIdx.x;   // 0..12287
    int mat = idx >> 12, fp = idx & 4095;
    int tile = fp >> 6, lane = fp & 63;
    const float* src;
    if (mat == 1) {                 // W1_1: [256][128], 8mt x 8kt
        int mt = tile >> 3, kt = tile & 7;
        src = W1b + (32 * mt + (lane & 31)) * 128 + 16 * kt + 8 * (lane >> 5);
    } else {                        // W2-type: [128][256], 4mt x 16kt
        const float* W = (mat == 0) ? W2a : W2b;
        int mt = tile >> 4, kt = tile & 15;
        src = W + (32 * mt + (lane & 31)) * 256 + 16 * kt + 8 * (lane >> 5);
    }
    unsigned short hs[8];
#pragma unroll
    for (int j = 0; j < 8; ++j) hs[j] = f2bh(src[j]);
    uint4 hv;
    hv.x = (unsigned)hs[0] | ((unsigned)hs[1] << 16);
    hv.y = (unsigned)hs[2] | ((unsigned)hs[3] << 16);
    hv.z = (unsigned)hs[4] | ((unsigned)hs[5] << 16);
    hv.w = (unsigned)hs[6] | ((unsigned)hs[7] << 16);
    F[idx] = hv;
}

__global__ __launch_bounds__(256) void k_z0(
    const float* __restrict__ cb, const float* __restrict__ bc,
    const float* __restrict__ WzT, float* __restrict__ z0,
    unsigned short* __restrict__ z0bf)
{
    int g = blockIdx.x * 256 + threadIdx.x;   // 0..32767
    int k = g >> 7, d = g & 127;
    float acc = bc[d] + cb[k * 128 + d];
    for (int j = 0; j < 128; ++j)
        acc = fmaf(cb[k * 128 + j], WzT[j * 128 + d], acc);
    z0[g] = acc;
    z0bf[g] = f2bh(acc);
}

__global__ __launch_bounds__(256) void k_u(
    const float* __restrict__ xhat, const float* __restrict__ WxT,
    float* __restrict__ u, unsigned short* __restrict__ ubf)
{
    int g = blockIdx.x * 256 + threadIdx.x;   // 0..262143
    int bl = g >> 7, d = g & 127;
    const float* xr = xhat + bl * 128;
    float acc = 0.f;
    for (int j = 0; j < 128; ++j)
        acc = fmaf(xr[j], WxT[j * 128 + d], acc);
    u[g] = acc;
    ubf[g] = f2bh(acc);
}

// H1f frags: H1pre[k][h] = W1_0[h] . z0[k], written bf16 in B-frag layout.
// block (kg,kt): lane holds col=k&31 (l31), h = 16kt + 8*(lane>>5) + j.
__global__ __launch_bounds__(256) void k_prehz(
    const float* __restrict__ z0, const float* __restrict__ W1a,
    unsigned short* __restrict__ H1f)
{
    __shared__ float s[4][128];
    const int t = threadIdx.x;
    const int r0 = blockIdx.x * 4;   // k rows
#pragma unroll
    for (int e = t; e < 512; e += 256)
        s[e >> 7][e & 127] = z0[(r0 + (e >> 7)) * 128 + (e & 127)];
    __syncthreads();
    float a[4] = {0.f, 0.f, 0.f, 0.f};
    const float* wr = W1a + t * 128;
    for (int i = 0; i < 128; i += 4) {
        float4 w = *(const float4*)(wr + i);
#pragma unroll
        for (int r = 0; r < 4; ++r)
            a[r] = fmaf(s[r][i], w.x, fmaf(s[r][i+1], w.y, fmaf(s[r][i+2], w.z, fmaf(s[r][i+3], w.w, a[r]))));
    }
    const int kt = t >> 4, half = (t >> 3) & 1, j = t & 7;
#pragma unroll
    for (int r = 0; r < 4; ++r) {
        int k = r0 + r; int kg = k >> 5, col = k & 31;
        H1f[((((kg << 4) + kt) << 6) + (half << 5) + col) * 8 + j] = f2bh(a[r]);
    }
}

// U1bf[b][h] = bf16( W1_0[h] . u[b] )
__global__ __launch_bounds__(256) void k_prehu(
    const float* __restrict__ u, const float* __restrict__ W1a,
    unsigned short* __restrict__ U1bf)
{
    __shared__ float s[4][128];
    const int t = threadIdx.x;
    const int r0 = blockIdx.x * 4;   // b rows
#pragma unroll
    for (int e = t; e < 512; e += 256)
        s[e >> 7][e & 127] = u[(r0 + (e >> 7)) * 128 + (e & 127)];
    __syncthreads();
    float a[4] = {0.f, 0.f, 0.f, 0.f};
    const float* wr = W1a + t * 128;
    for (int i = 0; i < 128; i += 4) {
        float4 w = *(const float4*)(wr + i);
#pragma unroll
        for (int r = 0; r < 4; ++r)
            a[r] = fmaf(s[r][i], w.x, fmaf(s[r][i+1], w.y, fmaf(s[r][i+2], w.z, fmaf(s[r][i+3], w.w, a[r]))));
    }
#pragma unroll
    for (int r = 0; r < 4; ++r)
        U1bf[(r0 + r) * 256 + t] = f2bh(a[r]);
}

// ---------------- approx dist (hi-only bf16 MFMA) ----------------
// 512 thr / 8 waves; wg = (b, 128-code half q). wave: wm=wave&3 (d-tile), wn=wave>>2.
// zs[2]: colgroups {2wn, 2wn+1}. Frag block = 64 uint4 (hi only).
__global__ __launch_bounds__(512, 6) void k_dist_approx(
    const unsigned short* __restrict__ z0bf, const unsigned short* __restrict__ ubf,
    const float* __restrict__ xhat, const float* __restrict__ x,
    const uint4* __restrict__ H1f, const unsigned short* __restrict__ U1bf,
    const uint4* __restrict__ W2f0, const uint4* __restrict__ W1f1,
    const uint4* __restrict__ W2f1, float* __restrict__ dist)
{
    __shared__ uint4 Zf[2048];   // 32 KB: blocks (gabs*8 + kt)
    __shared__ uint4 Hf[1024];   // 16 KB: blocks (gabs*4 + ktl); union: red[512] at end

    const int t = threadIdx.x;
    const int lane = t & 63, wave = t >> 6;
    const int wm = wave & 3, wn = wave >> 2;
    const int l31 = lane & 31, l5 = lane >> 5;
    const int b = blockIdx.x >> 1, q = blockIdx.x & 1;
    const int k0 = q << 7;

    // init zs = bf(z0[k]) + bf(u[b]) at C-frag positions (d = 32wm+8rg+4l5+j)
    f32x16 zs[2];
    {
        const unsigned short* ur = ubf + b * 128;
#pragma unroll
        for (int g = 0; g < 2; ++g) {
            const int colw = ((wn << 1) + g) * 32 + l31;
            const unsigned short* zr = z0bf + (k0 + colw) * 128;
#pragma unroll
            for (int rg = 0; rg < 4; ++rg) {
                const int d0 = 32 * wm + 8 * rg + 4 * l5;
                ushort4 a = *(const ushort4*)(zr + d0);
                ushort4 c = *(const ushort4*)(ur + d0);
                zs[g][4*rg+0] = bh2f(a.x) + bh2f(c.x);
                zs[g][4*rg+1] = bh2f(a.y) + bh2f(c.y);
                zs[g][4*rg+2] = bh2f(a.z) + bh2f(c.z);
                zs[g][4*rg+3] = bh2f(a.w) + bh2f(c.w);
            }
        }
    }

    // P0: blk0-G2: zs += W2_0 . relu(H1pre+U1)^T, 4 rounds of 4 kt
#pragma unroll 1
    for (int r = 0; r < 4; ++r) {
        {   // stage: wave covers blocks (gabs = 2wn+gi, slot wm), kt = 4r+wm
            const int kt = 4 * r + wm;
            const uint4 uv = *(const uint4*)(U1bf + b * 256 + kt * 16 + 8 * l5);
#pragma unroll
            for (int gi = 0; gi < 2; ++gi) {
                const int gabs = 2 * wn + gi;
                const int kg = (q << 2) + gabs;
                uint4 hv = H1f[(((kg << 4) + kt) << 6) + lane];
                uint4 o;
                o.x = addrelu2(hv.x, uv.x);
                o.y = addrelu2(hv.y, uv.y);
                o.z = addrelu2(hv.z, uv.z);
                o.w = addrelu2(hv.w, uv.w);
                Hf[((gabs << 2) + wm) * 64 + lane] = o;
            }
        }
        __syncthreads();
#pragma unroll
        for (int ktl = 0; ktl < 4; ++ktl) {
            uint4 ah = W2f0[((wm << 4) + 4 * r + ktl) * 64 + lane];
#pragma unroll
            for (int g = 0; g < 2; ++g) {
                uint4 bv = Hf[((((wn << 1) + g) << 2) + ktl) * 64 + lane];
                zs[g] = mfma_bf(ah, bv, zs[g]);
            }
        }
        __syncthreads();
    }

    // P1: write z1 (RNE bf16) to Zf in B-frag order
#pragma unroll
    for (int g = 0; g < 2; ++g) {
        const int gabs = (wn << 1) + g;
#pragma unroll
        for (int rg = 0; rg < 4; ++rg) {
            uint2 hv;
            hv.x = pack2(zs[g][4*rg+0], zs[g][4*rg+1]);
            hv.y = pack2(zs[g][4*rg+2], zs[g][4*rg+3]);
            uint2* zb2 = (uint2*)&Zf[((gabs << 3) + 2 * wm + (rg >> 1)) * 64];
            zb2[(((rg & 1) << 5) + l31) * 2 + l5] = hv;
        }
    }
    __syncthreads();

    // P2: blk1, 4 chunks of 64 h. G1: wave -> h-tile (2c + (wave&1)), cg (wave>>1).
    const int tile = wave & 1, cg = wave >> 1;
#pragma unroll 1
    for (int c = 0; c < 4; ++c) {
        f32x16 acc;
#pragma unroll
        for (int rr = 0; rr < 16; ++rr) acc[rr] = 0.f;
        const uint4* pw1 = W1f1 + ((2 * c + tile) << 3) * 64;
#pragma unroll
        for (int kt = 0; kt < 8; ++kt) {
            uint4 bv = Zf[((cg << 3) + kt) * 64 + lane];
            uint4 ah = pw1[kt * 64 + lane];
            acc = mfma_bf(ah, bv, acc);
        }
        __syncthreads();   // G2(c-1) readers done before Hf overwrite
#pragma unroll
        for (int rg = 0; rg < 4; ++rg) {
            float v0 = fmaxf(acc[4*rg+0], 0.f), v1 = fmaxf(acc[4*rg+1], 0.f);
            float v2 = fmaxf(acc[4*rg+2], 0.f), v3 = fmaxf(acc[4*rg+3], 0.f);
            uint2 hv; hv.x = pack2(v0, v1); hv.y = pack2(v2, v3);
            uint2* hb2 = (uint2*)&Hf[((cg << 2) + (tile << 1) + (rg >> 1)) * 64];
            hb2[(((rg & 1) << 5) + l31) * 2 + l5] = hv;
        }
        __syncthreads();
#pragma unroll
        for (int ktl = 0; ktl < 4; ++ktl) {
            uint4 ah = W2f1[((wm << 4) + 4 * c + ktl) * 64 + lane];
#pragma unroll
            for (int g = 0; g < 2; ++g) {
                uint4 bv = Hf[((((wn << 1) + g) << 2) + ktl) * 64 + lane];
                zs[g] = mfma_bf(ah, bv, zs[g]);
            }
        }
    }

    // P3: approx dist
    float* red = (float*)Hf;   // [4][128]
    __syncthreads();
#pragma unroll
    for (int g = 0; g < 2; ++g) {
        float s = 0.f;
        const int colw = ((wn << 1) + g) * 32 + l31;
#pragma unroll
        for (int rg = 0; rg < 4; ++rg) {
            const int d0 = 32 * wm + 8 * rg + 4 * l5;
            float4 xh = *(const float4*)(xhat + b * 128 + d0);
            float4 xx = *(const float4*)(x + b * 128 + d0);
            float v;
            v = zs[g][4*rg+0] + xh.x - xx.x; s = fmaf(v, v, s);
            v = zs[g][4*rg+1] + xh.y - xx.y; s = fmaf(v, v, s);
            v = zs[g][4*rg+2] + xh.z - xx.z; s = fmaf(v, v, s);
            v = zs[g][4*rg+3] + xh.w - xx.w; s = fmaf(v, v, s);
        }
        s += __shfl_xor(s, 32, 64);
        if (l5 == 0) red[wm * 128 + colw] = s;
    }
    __syncthreads();
    if (t < 128)
        dist[b * 256 + k0 + t] = red[t] + red[128 + t] + red[256 + t] + red[384 + t];
}

// ---------------- candidate selection ----------------
__global__ __launch_bounds__(64) void k_select(
    const float* __restrict__ dist, int* __restrict__ cand_k,
    int* __restrict__ cand_cnt, int2* __restrict__ pairs, int* __restrict__ npairs)
{
    __shared__ int sk[8];
    const int b = blockIdx.x, lane = threadIdx.x;
    float v0 = dist[b * 256 + lane];
    float v1 = dist[b * 256 + 64 + lane];
    float v2 = dist[b * 256 + 128 + lane];
    float v3 = dist[b * 256 + 192 + lane];
    float m = fminf(fminf(v0, v1), fminf(v2, v3));
#pragma unroll
    for (int off = 32; off > 0; off >>= 1) m = fminf(m, __shfl_xor(m, off, 64));
    const float thr = m + DELTA;
    const unsigned long long below = (1ull << lane) - 1;
    float vv[4] = {v0, v1, v2, v3};
    int base = 0;
#pragma unroll
    for (int j = 0; j < 4; ++j) {
        bool p = vv[j] <= thr;
        unsigned long long mask = __ballot(p);
        int pos = base + __popcll(mask & below);
        if (p && pos < 8) sk[pos] = 64 * j + lane;
        base += __popcll(mask);
    }
    __syncthreads();
    if (lane == 0) {
        int c = base > 8 ? 8 : base;
        cand_cnt[b] = c;
        int off = atomicAdd(npairs, c);
        for (int s = 0; s < c; ++s) {
            cand_k[b * 8 + s] = sk[s];
            pairs[off + s] = make_int2(b, (sk[s] << 4) | s);
        }
    }
}

// ---------------- exact f32 recompute of candidate dists (8 pairs/wg) ----------------
__global__ __launch_bounds__(256) void k_exact(
    const float* __restrict__ z0, const float* __restrict__ u,
    const float* __restrict__ xhat, const float* __restrict__ x,
    const int2* __restrict__ pairs, const int* __restrict__ npairs,
    const float* __restrict__ W1Ta, const float* __restrict__ W2Ta,
    const float* __restrict__ W1Tb, const float* __restrict__ W2Tb,
    float* __restrict__ ex_dist)
{
    __shared__ float z8[8][128];
    __shared__ float h8[8][256];
    __shared__ int pb[8], pk[8], psl[8];
    __shared__ int scnt;
    __shared__ float part[8][32];
    const int t = threadIdx.x;
    if (t == 0) {
        int np = *npairs; if (np > 16384) np = 16384;
        int c = np - (int)blockIdx.x * 8;
        scnt = c < 0 ? 0 : (c > 8 ? 8 : c);
    }
    __syncthreads();
    const int cnt = scnt;
    if (cnt == 0) return;
    if (t < 8) {
        int idx = blockIdx.x * 8 + (t < cnt ? t : cnt - 1);
        int2 p = pairs[idx];
        pb[t] = p.x; pk[t] = p.y >> 4; psl[t] = p.y & 15;
    }
    __syncthreads();
#pragma unroll
    for (int n = 0; n < 4; ++n) {
        int e = n * 256 + t; int r = e >> 7, d = e & 127;
        z8[r][d] = z0[pk[r] * 128 + d] + u[pb[r] * 128 + d];
    }
    __syncthreads();
    const float* W1T = W1Ta; const float* W2T = W2Ta;
#pragma unroll 1
    for (int blk = 0; blk < 2; ++blk) {
        float a1[8] = {0.f,0.f,0.f,0.f,0.f,0.f,0.f,0.f};
        for (int d = 0; d < 128; ++d) {
            const float w = W1T[d * 256 + t];
#pragma unroll
            for (int r = 0; r < 8; ++r) a1[r] = fmaf(z8[r][d], w, a1[r]);
        }
#pragma unroll
        for (int r = 0; r < 8; ++r) h8[r][t] = fmaxf(a1[r], 0.f);
        __syncthreads();
        const int ig = t & 127, rg = (t >> 7) * 4;
        float a2[4] = {0.f,0.f,0.f,0.f};
        for (int h = 0; h < 256; ++h) {
            const float w = W2T[h * 128 + ig];
#pragma unroll
            for (int j = 0; j < 4; ++j) a2[j] = fmaf(h8[rg + j][h], w, a2[j]);
        }
        __syncthreads();
#pragma unroll
        for (int j = 0; j < 4; ++j) z8[rg + j][ig] += a2[j];
        __syncthreads();
        W1T = W1Tb; W2T = W2Tb;
    }
    {
        const int r = t >> 5, c = t & 31;
        const int br = pb[r];
        float s = 0.f;
#pragma unroll
        for (int i = 0; i < 4; ++i) {
            int d = c * 4 + i;
            float v = z8[r][d] + xhat[br * 128 + d] - x[br * 128 + d];
            s = fmaf(v, v, s);
        }
        part[r][c] = s;
    }
    __syncthreads();
    if (t < 8 && t < cnt) {
        float s = 0.f;
#pragma unroll
        for (int c2 = 0; c2 < 32; ++c2) s += part[t][c2];
        ex_dist[pb[t] * 8 + psl[t]] = s;
    }
}

// ---------------- pick winner (slots are k-ascending; strict < keeps lowest k) ----------------
__global__ __launch_bounds__(256) void k_pick(
    const int* __restrict__ cand_k, const int* __restrict__ cand_cnt,
    const float* __restrict__ ex_dist, int* __restrict__ codes,
    float* __restrict__ out0)
{
    int b = blockIdx.x * 256 + threadIdx.x;
    int cnt = cand_cnt[b];
    float bv = ex_dist[b * 8]; int bk = cand_k[b * 8];
    for (int s = 1; s < cnt; ++s) {
        float v = ex_dist[b * 8 + s];
        if (v < bv) { bv = v; bk = cand_k[b * 8 + s]; }
    }
    codes[b] = bk;
    out0[b] = (float)bk;
}

// ---------------- winner recompute (f32-exact) ----------------
__global__ __launch_bounds__(256) void k_final(
    const float* __restrict__ z0, const float* __restrict__ u,
    const int* __restrict__ codes,
    const float* __restrict__ W1Ta, const float* __restrict__ W2Ta,
    const float* __restrict__ W1Tb, const float* __restrict__ W2Tb,
    float* __restrict__ outd)
{
    __shared__ float z8[8][128];
    __shared__ float h8[8][256];
    __shared__ int ci[8];
    const int t = threadIdx.x;
    const int b0 = blockIdx.x * 8;
    if (t < 8) ci[t] = codes[b0 + t];
    __syncthreads();
#pragma unroll
    for (int n = 0; n < 4; ++n) {
        int e = n * 256 + t; int r = e >> 7, d = e & 127;
        z8[r][d] = z0[ci[r] * 128 + d] + u[(b0 + r) * 128 + d];
    }
    __syncthreads();
    const float* W1T = W1Ta; const float* W2T = W2Ta;
#pragma unroll 1
    for (int blk = 0; blk < 2; ++blk) {
        float a1[8] = {0.f,0.f,0.f,0.f,0.f,0.f,0.f,0.f};
        for (int d = 0; d < 128; ++d) {
            const float w = W1T[d * 256 + t];
#pragma unroll
            for (int r = 0; r < 8; ++r) a1[r] = fmaf(z8[r][d], w, a1[r]);
        }
#pragma unroll
        for (int r = 0; r < 8; ++r) h8[r][t] = fmaxf(a1[r], 0.f);
        __syncthreads();
        const int ig = t & 127, rg = (t >> 7) * 4;
        float a2[4] = {0.f,0.f,0.f,0.f};
        for (int h = 0; h < 256; ++h) {
            const float w = W2T[h * 128 + ig];
#pragma unroll
            for (int j = 0; j < 4; ++j) a2[j] = fmaf(h8[rg + j][h], w, a2[j]);
        }
        __syncthreads();
#pragma unroll
        for (int j = 0; j < 4; ++j) z8[rg + j][ig] += a2[j];
        __syncthreads();
        W1T = W1Tb; W2T = W2Tb;
    }
#pragma unroll
    for (int n = 0; n < 4; ++n) {
        int e = n * 256 + t; int r = e >> 7, d = e & 127;
        outd[(b0 + r) * 128 + d] = z8[r][d];
    }
}

extern "C" void kernel_launch(void* const* d_in, const int* in_sizes, int n_in,
                              void* d_out, int out_size, void* d_ws, size_t ws_size,
                              hipStream_t stream) {
    const float* xhat = (const float*)d_in[0];
    const float* x    = (const float*)d_in[1];
    const float* cb   = (const float*)d_in[2];
    const float* Wc   = (const float*)d_in[3];
    const float* bc   = (const float*)d_in[4];
    const float* W1_0 = (const float*)d_in[5];
    const float* W2_0 = (const float*)d_in[6];
    const float* W1_1 = (const float*)d_in[7];
    const float* W2_1 = (const float*)d_in[8];
    float* out = (float*)d_out;
    float* ws  = (float*)d_ws;

    float* WzT   = ws + 0;
    float* WxT   = ws + 16384;
    float* W1T0  = ws + 32768;
    float* W2T0  = ws + 65536;
    float* W1T1  = ws + 98304;
    float* W2T1  = ws + 131072;
    float* z0    = ws + 163840;
    float* u     = ws + 196608;
    float* dist  = ws + 458752;
    unsigned short* z0bf = (unsigned short*)(ws + 983040);
    unsigned short* ubf  = (unsigned short*)(ws + 999424);
    unsigned short* U1bf = (unsigned short*)(ws + 1130496);
    uint4* H1f   = (uint4*)(ws + 1392640);
    uint4* F     = (uint4*)(ws + 1425408);
    const uint4* W2f0 = F;
    const uint4* W1f1 = F + 4096;
    const uint4* W2f1 = F + 8192;
    int*   cand_k   = (int*)(ws + 1474560);
    int*   cand_cnt = (int*)(ws + 1490944);
    float* ex_dist  = ws + 1492992;
    int2*  pairs    = (int2*)(ws + 1509376);
    int*   npairs   = (int*)(ws + 1542144);
    int*   codes    = (int*)(ws + 1542148);

    k_transpose<<<640, 256, 0, stream>>>(Wc, W1_0, W2_0, W1_1, W2_1,
                                         WzT, WxT, W1T0, W2T0, W1T1, W2T1);
    k_pack<<<48, 256, 0, stream>>>(W2_0, W1_1, W2_1, F);
    k_z0<<<128, 256, 0, stream>>>(cb, bc, WzT, z0, z0bf);
    k_u<<<1024, 256, 0, stream>>>(xhat, WxT, u, ubf);
    k_prehz<<<64, 256, 0, stream>>>(z0, W1_0, (unsigned short*)H1f);
    k_prehu<<<512, 256, 0, stream>>>(u, W1_0, U1bf);
    k_dist_approx<<<4096, 512, 0, stream>>>(z0bf, ubf, xhat, x, H1f, U1bf,
                                            W2f0, W1f1, W2f1, dist);
    hipMemsetAsync(npairs, 0, sizeof(int), stream);
    k_select<<<2048, 64, 0, stream>>>(dist, cand_k, cand_cnt, pairs, npairs);
    k_exact<<<2048, 256, 0, stream>>>(z0, u, xhat, x, pairs, npairs,
                                      W1T0, W2T0, W1T1, W2T1, ex_dist);
    k_pick<<<8, 256, 0, stream>>>(cand_k, cand_cnt, ex_dist, codes, out);
    k_final<<<256, 256, 0, stream>>>(z0, u, codes, W1T0, W2T0, W1T1, W2T1, out + 2048);
}